// Round 8
// baseline (353.925 us; speedup 1.0000x reference)
//
#include <hip/hip_runtime.h>
#include <math.h>

// Problem constants
#define N_ROT 32      // 8 inclinations x 4 azimuths
#define O_CH 16
#define I_CH 8
#define KVOL 27
#define DHW 40
#define SPATIAL (DHW*DHW*DHW)        // 64000
#define OUT_PLANE (2*O_CH*SPATIAL)   // 2048000 elements per output tensor
#define PDHW 42
#define PSPAT (PDHW*PDHW*PDHW)       // 74088 padded spatial
#define WROT_ELEMS (O_CH*KVOL*I_CH*N_ROT)   // 110592 floats = 442368 B
#define XPAD_ELEMS (2*PSPAT*I_CH)           // NDHWC padded: 1185408 floats

typedef float f32x2 __attribute__((ext_vector_type(2)));

// ---------------------------------------------------------------------------
// Kernel 1: rotated weights wrot[o][k][ci][r], k = kz*9+ky*3+kx.
// UNCHANGED from the passing R4-R7 kernels — bit pattern is load-bearing.
// ---------------------------------------------------------------------------
__global__ void build_wrot(const float* __restrict__ w, float* __restrict__ wrot) {
    int tid = blockIdx.x * blockDim.x + threadIdx.x;
    if (tid >= N_ROT * KVOL) return;
    int r = tid / KVOL, p = tid % KVOL;
    int th = r / 4, ph = r % 4;
    double theta = ((double)th * 22.5) * (M_PI / 180.0);   // np.deg2rad
    double phi   = ((double)ph * 90.0) * (M_PI / 180.0);
    double ct = cos(theta), st = sin(theta);
    double cp = cos(phi),   sp = sin(phi);
    double R00 = cp*ct, R01 = -sp, R02 = cp*st;
    double R10 = sp*ct, R11 =  cp, R12 = sp*st;
    double R20 = -st,   R21 = 0.0, R22 = ct;
    double d0 = (double)(p / 9) - 1.0;
    double d1 = (double)((p / 3) % 3) - 1.0;
    double d2 = (double)(p % 3) - 1.0;
    double s0 = d0*R00 + d1*R10 + d2*R20 + 1.0;
    double s1 = d0*R01 + d1*R11 + d2*R21 + 1.0;
    double s2 = d0*R02 + d1*R12 + d2*R22 + 1.0;
    double f0 = floor(s0), f1 = floor(s1), f2 = floor(s2);
    double w0 = s0 - f0, w1 = s1 - f1, w2 = s2 - f2;
    int i0 = (int)f0, i1 = (int)f1, i2 = (int)f2;

    float tq[KVOL];
    #pragma unroll
    for (int q = 0; q < KVOL; q++) tq[q] = 0.0f;

    for (int dz = 0; dz < 2; dz++)
      for (int dy = 0; dy < 2; dy++)
        for (int dx = 0; dx < 2; dx++) {
            int n0 = i0 + dz, n1 = i1 + dy, n2 = i2 + dx;
            bool valid = (n0 >= 0 && n0 < 3 && n1 >= 0 && n1 < 3 && n2 >= 0 && n2 < 3);
            double wt = (dz ? w0 : 1.0 - w0) * (dy ? w1 : 1.0 - w1) * (dx ? w2 : 1.0 - w2);
            int lin = n0 * 9 + n1 * 3 + n2;
            lin = lin < 0 ? 0 : (lin > 26 ? 26 : lin);   // np.clip
            if (valid) tq[lin] += (float)wt;
        }

    for (int o = 0; o < O_CH; o++) {
        for (int i = 0; i < I_CH; i++) {
            const float* wf = w + (o * I_CH + i) * KVOL;
            float acc = 0.0f;
            for (int q = 0; q < KVOL; q++)
                acc = fmaf(tq[q], wf[q], acc);   // f32 fma chain, ascending q
            wrot[((o * KVOL + p) * I_CH + i) * N_ROT + r] = acc;
        }
    }
}

// ---------------------------------------------------------------------------
// Kernel 1b: zero-pad + transpose x (NCDHW 40^3) -> xp (NDHWC 42^3).
// Padding +0.0f = exact fma no-op (proven chain-neutral R4 vs R5).
// ---------------------------------------------------------------------------
__global__ void pad_x(const float* __restrict__ x, float* __restrict__ xp) {
    int idx = blockIdx.x * blockDim.x + threadIdx.x;
    if (idx >= XPAD_ELEMS) return;
    int ci = idx & 7;
    int s  = (idx >> 3) % PSPAT;
    int b  = idx / (8 * PSPAT);
    int xq = s % PDHW;
    int yq = (s / PDHW) % PDHW;
    int zq = s / (PDHW * PDHW);
    float v = 0.0f;
    if (xq >= 1 && xq <= DHW && yq >= 1 && yq <= DHW && zq >= 1 && zq <= DHW)
        v = x[((b * I_CH + ci) * SPATIAL) + ((zq - 1) * DHW + (yq - 1)) * DHW + (xq - 1)];
    xp[idx] = v;
}

// ---------------------------------------------------------------------------
// Kernel 2: conv3d with XLA-CPU-identical f32 fma chains + argmax + epilogue.
// 128 threads/block = 8(x) x 8(y) x 2(lz); FOUR z-voxels per thread, packed
// as two f32x2 accumulator sets -> LLVM can emit v_pk_fma_f32 (dual-rate
// fp32). Each vector half is an independent voxel's chain; per-chain order
// (kz,ky,kx,ci ascending, IEEE fma) is bit-identical to R4-R7.
// Weights: wave-uniform indices -> s_load (SMEM pipe), amortized over 4 vox.
// ---------------------------------------------------------------------------
template<bool PADDED>
__global__ __launch_bounds__(128, 2) void conv_max_epi(
        const float* __restrict__ xg,
        const float* __restrict__ wrot,
        float* __restrict__ out) {
    int blk = blockIdx.x;
    int tx = blk % 5; blk /= 5;
    int ty = blk % 5; blk /= 5;
    int tz = blk % 5; blk /= 5;
    int o  = blk % O_CH; blk /= O_CH;
    int b  = blk;

    int lt = threadIdx.x;
    int lx = lt & 7;
    int ly = (lt >> 3) & 7;
    int lz = lt >> 6;                 // 0..1
    int xx = tx * 8 + lx;
    int yy = ty * 8 + ly;
    int zb = tz * 8 + lz * 4;         // voxels zb..zb+3

    f32x2 accA[N_ROT], accB[N_ROT];   // A = voxels (zb, zb+1), B = (zb+2, zb+3)
    #pragma unroll
    for (int r = 0; r < N_ROT; r++) {
        accA[r] = (f32x2){0.0f, 0.0f};
        accB[r] = (f32x2){0.0f, 0.0f};
    }

    const float* __restrict__ wo = wrot + o * (KVOL * I_CH * N_ROT);

    if (PADDED) {
        const float* __restrict__ xb = xg + (size_t)b * (8 * PSPAT);
        const int F4Z = PDHW * PDHW * 2;   // float4 stride per +1 z
        #pragma clang loop unroll(disable)
        for (int k = 0; k < KVOL; k++) {
            int kz = k / 9, ky = (k / 3) % 3, kx = k % 3;
            int sb = ((zb + kz) * PDHW + (yy + ky)) * PDHW + (xx + kx);
            const float4* p = (const float4*)(xb + (size_t)sb * 8);
            float4 q0a = p[0],         q0b = p[1];
            float4 q1a = p[F4Z],       q1b = p[F4Z + 1];
            float4 q2a = p[2 * F4Z],   q2b = p[2 * F4Z + 1];
            float4 q3a = p[3 * F4Z],   q3b = p[3 * F4Z + 1];
            float xv0[8] = {q0a.x, q0a.y, q0a.z, q0a.w, q0b.x, q0b.y, q0b.z, q0b.w};
            float xv1[8] = {q1a.x, q1a.y, q1a.z, q1a.w, q1b.x, q1b.y, q1b.z, q1b.w};
            float xv2[8] = {q2a.x, q2a.y, q2a.z, q2a.w, q2b.x, q2b.y, q2b.z, q2b.w};
            float xv3[8] = {q3a.x, q3a.y, q3a.z, q3a.w, q3b.x, q3b.y, q3b.z, q3b.w};
            const float* __restrict__ wk = wo + k * (I_CH * N_ROT);
            #pragma unroll
            for (int ci = 0; ci < I_CH; ci++) {
                f32x2 xA = {xv0[ci], xv1[ci]};
                f32x2 xB = {xv2[ci], xv3[ci]};
                const float* __restrict__ wp = wk + ci * N_ROT;
                #pragma unroll
                for (int r = 0; r < N_ROT; r++) {
                    float wv = wp[r];            // wave-uniform -> SGPR
                    f32x2 w2 = {wv, wv};
                    accA[r] = __builtin_elementwise_fma(xA, w2, accA[r]);
                    accB[r] = __builtin_elementwise_fma(xB, w2, accB[r]);
                }
            }
        }
    } else {
        // fallback (ws too small): bounds-checked NCDHW, same per-voxel chains
        const float* __restrict__ xb = xg + (size_t)b * I_CH * SPATIAL;
        #pragma clang loop unroll(disable)
        for (int k = 0; k < KVOL; k++) {
            int kz = k / 9, ky = (k / 3) % 3, kx = k % 3;
            int z0 = zb + kz - 1;
            int yv = yy + ky - 1;
            int xv = xx + kx - 1;
            bool xyok = ((unsigned)yv < DHW) && ((unsigned)xv < DHW);
            int sbase = (z0 * DHW + yv) * DHW + xv;
            const float* __restrict__ wk = wo + k * (I_CH * N_ROT);
            #pragma clang loop unroll(disable)
            for (int ci = 0; ci < I_CH; ci++) {
                const float* xc = xb + ci * SPATIAL;
                float xs[4];
                #pragma unroll
                for (int v = 0; v < 4; v++) {
                    bool ok = xyok && ((unsigned)(z0 + v) < DHW);
                    xs[v] = ok ? xc[sbase + v * DHW * DHW] : 0.0f;
                }
                f32x2 xA = {xs[0], xs[1]};
                f32x2 xB = {xs[2], xs[3]};
                const float* __restrict__ wp = wk + ci * N_ROT;
                #pragma unroll
                for (int r = 0; r < N_ROT; r++) {
                    float wv = wp[r];
                    f32x2 w2 = {wv, wv};
                    accA[r] = __builtin_elementwise_fma(xA, w2, accA[r]);
                    accB[r] = __builtin_elementwise_fma(xB, w2, accB[r]);
                }
            }
        }
    }

    // epilogue (bit-identical semantics to R4-R7): first-max argmax, relu, trig
    #pragma unroll
    for (int v = 0; v < 4; v++) {
        float best = (v < 2) ? accA[0][v & 1] : accB[0][v & 1];
        int bi = 0;
        #pragma unroll
        for (int r = 1; r < N_ROT; r++) {
            float val = (v < 2) ? accA[r][v & 1] : accB[r][v & 1];
            if (val > best) { best = val; bi = r; }
        }
        float s = best > 0.0f ? best : 0.0f;
        float ang = (float)bi * (float)(M_PI / 4.0);
        float sa = sinf(ang), ca = cosf(ang);
        int oidx = ((b * O_CH + o) * SPATIAL) + ((zb + v) * DHW + yy) * DHW + xx;
        out[oidx]                 = s * sa * ca;
        out[oidx + OUT_PLANE]     = s * sa * sa;
        out[oidx + 2 * OUT_PLANE] = s * ca;
    }
}

extern "C" void kernel_launch(void* const* d_in, const int* in_sizes, int n_in,
                              void* d_out, int out_size, void* d_ws, size_t ws_size,
                              hipStream_t stream) {
    const float* x = (const float*)d_in[0];      // [2,8,40,40,40]
    const float* w = (const float*)d_in[1];      // [16,8,3,3,3]
    float* out = (float*)d_out;                  // u,v,w concatenated
    float* wrot = (float*)d_ws;                  // [16][27][8][32] f32

    const size_t wrot_bytes = (size_t)WROT_ELEMS * 4;
    const size_t need = wrot_bytes + (size_t)XPAD_ELEMS * 4;

    build_wrot<<<(N_ROT * KVOL + 255) / 256, 256, 0, stream>>>(w, wrot);

    int grid = 5 * 5 * 5 * O_CH * 2;   // 4000 blocks of 128 threads

    if (ws_size >= need) {
        float* xp = (float*)((char*)d_ws + wrot_bytes);
        pad_x<<<(XPAD_ELEMS + 255) / 256, 256, 0, stream>>>(x, xp);
        conv_max_epi<true><<<grid, 128, 0, stream>>>(xp, wrot, out);
    } else {
        conv_max_epi<false><<<grid, 128, 0, stream>>>(x, wrot, out);
    }
}